// Round 6
// baseline (161.124 us; speedup 1.0000x reference)
//
#include <hip/hip_runtime.h>
#include <hip/hip_bf16.h>

#define TT 2048
#define QSC 0.18033688011112042f   // 0.125 * log2(e)

typedef __attribute__((ext_vector_type(4))) float f32x4;
typedef __attribute__((ext_vector_type(8))) __bf16 bf16x8;
typedef __attribute__((ext_vector_type(4))) __bf16 bf16x4;

enum { M_CONV = 0, M_QKV = 1, M_PROJ = 2, M_FFN1 = 3, M_FFN2 = 4 };

__device__ __forceinline__ void gload16(const void* g, void* l) {
    __builtin_amdgcn_global_load_lds(
        (__attribute__((address_space(1))) void*)g,
        (__attribute__((address_space(3))) void*)l, 16, 0, 0);
}

__device__ __forceinline__ short f2bf(float f) {
    unsigned u = __float_as_uint(f);
    u = (u + 0x7fffu + ((u >> 16) & 1u)) >> 16;
    return (short)u;
}

// ---------------------------------------------------------------------------
// conv_w cast (semi-coalesced already) + padded x cast
// ---------------------------------------------------------------------------
__global__ void cast_all(const float* __restrict__ conv_w, const float* __restrict__ x,
                         short* __restrict__ cwT, short* __restrict__ xpad) {
    int idx = blockIdx.x * 256 + threadIdx.x;
    if (idx < 786432) {                       // conv_w OIH -> [o][tap*512+i]
        int tap = idx >> 18, i = (idx >> 9) & 511, o = idx & 511;
        cwT[(size_t)o * 1536 + tap * 512 + i] = f2bf(conv_w[((size_t)o * 512 + i) * 3 + tap]);
        return;
    }
    idx -= 786432;
    if (idx < 2099200) {                      // x -> xpad [2][2050][512] bf16
        int i = idx & 511, rp = idx >> 9;
        int bb = rp / 2050, rr = rp - bb * 2050;
        int t = rr - 2;
        float v = (t >= 0) ? x[((size_t)(bb << 11) + t) * 512 + i] : 0.f;
        xpad[((size_t)bb * 2050 + rr) * 512 + i] = f2bf(v);
    }
}

// ---------------------------------------------------------------------------
// Coalesced [K][N] -> [N][K] bf16 transposes via 32x32 LDS tiles.
// tiles: qkv 768 | proj 256 | ffn1 512 | ffn2 512  => 2048 blocks
// ---------------------------------------------------------------------------
__global__ __launch_bounds__(256) void transpose_cast(
    const float* __restrict__ qkv_w, const float* __restrict__ proj_w,
    const float* __restrict__ f1w, const float* __restrict__ f2w,
    short* __restrict__ qkvT, short* __restrict__ projT,
    short* __restrict__ f1T, short* __restrict__ f2T) {
    int t = blockIdx.x;
    const float* src; short* dst; int K, N, lt;
    if (t < 768)       { src = qkv_w;  dst = qkvT;  K = 512;  N = 1536; lt = t; }
    else if (t < 1024) { src = proj_w; dst = projT; K = 512;  N = 512;  lt = t - 768; }
    else if (t < 1536) { src = f1w;    dst = f1T;   K = 512;  N = 1024; lt = t - 1024; }
    else               { src = f2w;    dst = f2T;   K = 1024; N = 512;  lt = t - 1536; }
    int ntn = N >> 5;
    int kt = lt / ntn, nt = lt - kt * ntn;
    int k0 = kt * 32, n0 = nt * 32;
    __shared__ float tile[32][33];
    int c = threadIdx.x & 31, r = threadIdx.x >> 5;
    #pragma unroll
    for (int i = 0; i < 4; i++)
        tile[r + i * 8][c] = src[(size_t)(k0 + r + i * 8) * N + n0 + c];
    __syncthreads();
    #pragma unroll
    for (int i = 0; i < 4; i++)
        dst[(size_t)(n0 + r + i * 8) * K + k0 + c] = f2bf(tile[c][r + i * 8]);
}

// ---------------------------------------------------------------------------
// Row LayerNorm over C=512: f32 in -> f32 out + optional bf16 out
// ---------------------------------------------------------------------------
__global__ __launch_bounds__(256) void ln2_kernel(const float* __restrict__ in,
                                                  const float* __restrict__ g,
                                                  const float* __restrict__ b,
                                                  float* __restrict__ outf,
                                                  short* __restrict__ outb) {
    int row = blockIdx.x;
    int tid = threadIdx.x;
    const float* p = in + (size_t)row * 512;
    float2 v = *(const float2*)(p + tid * 2);
    float s = v.x + v.y;
    float ss = v.x * v.x + v.y * v.y;
    #pragma unroll
    for (int off = 1; off < 64; off <<= 1) {
        s  += __shfl_xor(s, off);
        ss += __shfl_xor(ss, off);
    }
    __shared__ float sm[4], sm2[4];
    int w = tid >> 6;
    if ((tid & 63) == 0) { sm[w] = s; sm2[w] = ss; }
    __syncthreads();
    s  = sm[0] + sm[1] + sm[2] + sm[3];
    ss = sm2[0] + sm2[1] + sm2[2] + sm2[3];
    float mean = s * (1.f / 512);
    float var  = ss * (1.f / 512) - mean * mean;
    float rstd = rsqrtf(var + 1e-5f);
    float2 gg = *(const float2*)(g + tid * 2);
    float2 bb = *(const float2*)(b + tid * 2);
    float ox = (v.x - mean) * rstd * gg.x + bb.x;
    float oy = (v.y - mean) * rstd * gg.y + bb.y;
    *(float2*)(outf + (size_t)row * 512 + tid * 2) = make_float2(ox, oy);
    if (outb) {
        unsigned pk = ((unsigned)(unsigned short)f2bf(oy) << 16) |
                      (unsigned)(unsigned short)f2bf(ox);
        *(unsigned*)&outb[(size_t)row * 512 + tid * 2] = pk;
    }
}

// ---------------------------------------------------------------------------
// A-operand global address (handles conv's padded/3-tap layout)
// ---------------------------------------------------------------------------
template<int MODE>
__device__ __forceinline__ const short* a_ptr(const short* A, int m0, int r, int kk, int K) {
    if constexpr (MODE == M_CONV) {
        int row = m0 + r;
        int bb = row >> 11, t5 = row & 2047;
        int tap = kk >> 9, k2 = kk & 511;
        return A + ((size_t)(bb * 2050 + t5 + tap) * 512 + k2);
    } else {
        return A + ((size_t)(m0 + r) * K + kk);
    }
}

// ---------------------------------------------------------------------------
// bf16 MFMA GEMM: BM=64, BN=64, BK=64, 2-phase pipeline: gload_lds prefetch
// of slab k+1 into the alternate LDS buffer issued BEFORE compute on slab k;
// one barrier per iter (its vmcnt(0) drain lands after the MFMAs).
// 4 waves (2x2), wave tile 32x32, chunk-swizzled LDS (c ^= r&7) both sides.
// ---------------------------------------------------------------------------
template<int MODE>
__global__ __launch_bounds__(256) void gemm_mfma(
    const short* __restrict__ A, const short* __restrict__ Bw,
    const float* __restrict__ bias, const float* __restrict__ res,
    void* __restrict__ Cout, short* __restrict__ vTb, int K) {
    __shared__ short As[2][64 * 64];
    __shared__ short Bs[2][64 * 64];
    const int tid = threadIdx.x;
    const int w = tid >> 6, l = tid & 63;
    const int wm = w >> 1, wn = w & 1;
    const int lr = l & 15, lc = l >> 4;
    const int m0 = blockIdx.x * 64, n0 = blockIdx.y * 64;
    f32x4 acc[2][2];
    #pragma unroll
    for (int mf = 0; mf < 2; mf++)
        #pragma unroll
        for (int nf = 0; nf < 2; nf++) acc[mf][nf] = (f32x4){0.f, 0.f, 0.f, 0.f};

    // prologue: stage slab 0
    #pragma unroll
    for (int i = 0; i < 2; i++) {
        int u = i * 256 + tid, r = u >> 3, c = (u & 7) ^ (r & 7);
        gload16(a_ptr<MODE>(A, m0, r, c * 8, K), (char*)As[0] + u * 16);
        gload16(Bw + ((size_t)(n0 + r) * K + c * 8), (char*)Bs[0] + u * 16);
    }
    __syncthreads();

    const int nit = K >> 6;
    for (int it = 0; it < nit; it++) {
        const int cur = it & 1;
        if (it + 1 < nit) {         // prefetch next slab into alt buffer
            int k0 = (it + 1) << 6;
            #pragma unroll
            for (int i = 0; i < 2; i++) {
                int u = i * 256 + tid, r = u >> 3, c = (u & 7) ^ (r & 7);
                gload16(a_ptr<MODE>(A, m0, r, k0 + c * 8, K), (char*)As[cur ^ 1] + u * 16);
                gload16(Bw + ((size_t)(n0 + r) * K + k0 + c * 8), (char*)Bs[cur ^ 1] + u * 16);
            }
        }
        bf16x8 af[2][2], bfv[2][2];
        #pragma unroll
        for (int mf = 0; mf < 2; mf++)
            #pragma unroll
            for (int ks = 0; ks < 2; ks++) {
                int rr = wm * 32 + mf * 16 + lr;
                int cc = (ks * 4 + lc) ^ (rr & 7);
                af[mf][ks] = *(const bf16x8*)&As[cur][rr * 64 + cc * 8];
            }
        #pragma unroll
        for (int nf = 0; nf < 2; nf++)
            #pragma unroll
            for (int ks = 0; ks < 2; ks++) {
                int rr = wn * 32 + nf * 16 + lr;
                int cc = (ks * 4 + lc) ^ (rr & 7);
                bfv[nf][ks] = *(const bf16x8*)&Bs[cur][rr * 64 + cc * 8];
            }
        __builtin_amdgcn_s_setprio(1);
        #pragma unroll
        for (int nf = 0; nf < 2; nf++)
            #pragma unroll
            for (int ks = 0; ks < 2; ks++)
                #pragma unroll
                for (int mf = 0; mf < 2; mf++)
                    acc[mf][nf] = __builtin_amdgcn_mfma_f32_16x16x32_bf16(
                        af[mf][ks], bfv[nf][ks], acc[mf][nf], 0, 0, 0);
        __builtin_amdgcn_s_setprio(0);
        __syncthreads();
    }
    // epilogue
    #pragma unroll
    for (int mf = 0; mf < 2; mf++) {
        int row0 = m0 + wm * 32 + mf * 16 + lc * 4;
        #pragma unroll
        for (int nf = 0; nf < 2; nf++) {
            int col = n0 + wn * 32 + nf * 16 + lr;
            float bv = bias[col];
            if constexpr (MODE == M_CONV || MODE == M_PROJ || MODE == M_FFN2) {
                float* Cf = (float*)Cout;
                #pragma unroll
                for (int rg = 0; rg < 4; rg++) {
                    size_t off = (size_t)(row0 + rg) * 512 + col;
                    Cf[off] = acc[mf][nf][rg] + bv + res[off];
                }
            } else if constexpr (MODE == M_FFN1) {
                short* Cb = (short*)Cout;
                #pragma unroll
                for (int rg = 0; rg < 4; rg++)
                    Cb[(size_t)(row0 + rg) * 1024 + col] =
                        f2bf(fmaxf(acc[mf][nf][rg] + bv, 0.f));
            } else {  // M_QKV
                short* Cb = (short*)Cout;
                float v[4];
                #pragma unroll
                for (int rg = 0; rg < 4; rg++) v[rg] = acc[mf][nf][rg] + bv;
                if (col < 512) {            // Q: pre-scaled into exp2 domain
                    #pragma unroll
                    for (int rg = 0; rg < 4; rg++)
                        Cb[(size_t)(row0 + rg) * 1536 + col] = f2bf(v[rg] * QSC);
                } else if (col < 1024) {    // K
                    #pragma unroll
                    for (int rg = 0; rg < 4; rg++)
                        Cb[(size_t)(row0 + rg) * 1536 + col] = f2bf(v[rg]);
                } else {                    // V -> vT[bh][d][t], kv-permuted in 64-tiles
                    int vc = col - 1024, hh = vc >> 6, dd = vc & 63;
                    int bb = row0 >> 11, t5 = row0 & 2047;
                    size_t basev = ((size_t)((bb << 3) + hh) * 64 + dd) * 2048 +
                                   (size_t)(t5 & ~63);
                    #pragma unroll
                    for (int rg = 0; rg < 4; rg++) {
                        int q = (t5 + rg) & 63;
                        int pp = ((q & 15) << 2) | (q >> 4);
                        vTb[basev + pp] = f2bf(v[rg]);
                    }
                }
            }
        }
    }
}

// ---------------------------------------------------------------------------
// bf16 MFMA flash attention, 512 blocks x 512 threads (8 waves), split-KV
// (waves 0-3 even kv tiles, 4-7 odd), LSE merge via LDS (aliased onto Ps).
// Q fragments held in registers (loaded once, pre-scaled by 0.125*log2e).
// P/V share a kv-permutation (p = (kv&15)*4 | kv>>4) so P stores are b64.
// LDS ~51KB -> 3 blocks/CU. exp2-domain softmax. defer-max THR=11.5 (log2).
// ---------------------------------------------------------------------------
__global__ __launch_bounds__(512, 6) void attn_mfma(const short* __restrict__ qkvb,
                                                    const short* __restrict__ vTb,
                                                    short* __restrict__ aout) {
    __shared__ short Ks[2][64 * 64];
    __shared__ short Vs[2][64 * 64];
    __shared__ short Ps[8 * 16 * 72];   // per-wave P; reused as float Osm[4][16][68]
    __shared__ float Mm[4][16], Lm[4][16];
    const int tid = threadIdx.x;
    const int w = tid >> 6, l = tid & 63;
    const int half = w >> 2, wq = w & 3;
    const int lr = l & 15, lc = l >> 4;
    const int L = blockIdx.x;
    const int bh = L & 15;
    const int qt = 31 - (L >> 4);
    const int b = bh >> 3, h = bh & 7;
    const int qr = wq * 16, q0 = qt * 64;
    const int pbase = w * (16 * 72);

    // Q fragments in registers (rows qr..qr+15 of this wave's Q band)
    bf16x8 aq[2];
    #pragma unroll
    for (int ks = 0; ks < 2; ks++)
        aq[ks] = *(const bf16x8*)(qkvb + (size_t)(b * 2048 + q0 + qr + lr) * 1536 +
                                  h * 64 + (lc + 4 * ks) * 8);

    f32x4 o[4];
    float mst[4], lst[4];
    #pragma unroll
    for (int nf = 0; nf < 4; nf++) o[nf] = (f32x4){0.f, 0.f, 0.f, 0.f};
    #pragma unroll
    for (int rg = 0; rg < 4; rg++) { mst[rg] = -1e30f; lst[rg] = 0.f; }

    const int NS = (qt + 2) >> 1;
    for (int ss = 0; ss < NS; ss++) {
        const int kt0 = 2 * ss, kt1 = 2 * ss + 1;
        {
            int u = tid, r = u >> 3, c = (u & 7) ^ (r & 7);
            gload16(qkvb + ((size_t)(b * 2048 + kt0 * 64 + r) * 1536 + 512 + h * 64 + c * 8),
                    (char*)Ks[0] + u * 16);
            gload16(vTb + ((size_t)(bh * 64 + r) * 2048 + kt0 * 64 + c * 8),
                    (char*)Vs[0] + u * 16);
            if (kt1 <= qt) {
                gload16(qkvb + ((size_t)(b * 2048 + kt1 * 64 + r) * 1536 + 512 + h * 64 + c * 8),
                        (char*)Ks[1] + u * 16);
                gload16(vTb + ((size_t)(bh * 64 + r) * 2048 + kt1 * 64 + c * 8),
                        (char*)Vs[1] + u * 16);
            }
        }
        __syncthreads();
        const int mykt = 2 * ss + half;
        if (mykt <= qt) {
            // ---- S = Q @ K^T (exp2-domain: Q pre-scaled) ----
            f32x4 s[4];
            #pragma unroll
            for (int nf = 0; nf < 4; nf++) s[nf] = (f32x4){0.f, 0.f, 0.f, 0.f};
            __builtin_amdgcn_s_setprio(1);
            #pragma unroll
            for (int nf = 0; nf < 4; nf++) {
                #pragma unroll
                for (int ks = 0; ks < 2; ks++) {
                    int rr = nf * 16 + lr;
                    int cc = (lc + 4 * ks) ^ (rr & 7);
                    bf16x8 bk = *(const bf16x8*)&Ks[half][rr * 64 + cc * 8];
                    s[nf] = __builtin_amdgcn_mfma_f32_16x16x32_bf16(aq[ks], bk, s[nf], 0, 0, 0);
                }
            }
            __builtin_amdgcn_s_setprio(0);
            // ---- online softmax, defer-max ----
            const bool diag = (mykt == qt);
            if (diag) {
                #pragma unroll
                for (int nf = 0; nf < 4; nf++)
                    #pragma unroll
                    for (int rg = 0; rg < 4; rg++)
                        if (nf * 16 + lr > qr + lc * 4 + rg) s[nf][rg] = -1e30f;
            }
            float rm[4];
            int ok = 1;
            #pragma unroll
            for (int rg = 0; rg < 4; rg++) {
                float m_ = fmaxf(fmaxf(s[0][rg], s[1][rg]), fmaxf(s[2][rg], s[3][rg]));
                m_ = fmaxf(m_, __shfl_xor(m_, 1));
                m_ = fmaxf(m_, __shfl_xor(m_, 2));
                m_ = fmaxf(m_, __shfl_xor(m_, 4));
                m_ = fmaxf(m_, __shfl_xor(m_, 8));
                rm[rg] = m_;
                ok &= (m_ <= mst[rg] + 11.5f);
            }
            if (!__all(ok)) {
                #pragma unroll
                for (int rg = 0; rg < 4; rg++) {
                    float mn = fmaxf(mst[rg], rm[rg]);
                    float alpha = exp2f(mst[rg] - mn);
                    mst[rg] = mn;
                    lst[rg] *= alpha;
                    #pragma unroll
                    for (int nf = 0; nf < 4; nf++) o[nf][rg] *= alpha;
                }
            }
            #pragma unroll
            for (int rg = 0; rg < 4; rg++) {
                float p0 = exp2f(s[0][rg] - mst[rg]);
                float p1 = exp2f(s[1][rg] - mst[rg]);
                float p2 = exp2f(s[2][rg] - mst[rg]);
                float p3 = exp2f(s[3][rg] - mst[rg]);
                bf16x4 pk4 = {(__bf16)p0, (__bf16)p1, (__bf16)p2, (__bf16)p3};
                *(bf16x4*)&Ps[pbase + (lc * 4 + rg) * 72 + lr * 4] = pk4;
                float rs = p0 + p1 + p2 + p3;
                rs += __shfl_xor(rs, 1);
                rs += __shfl_xor(rs, 2);
                rs += __shfl_xor(rs, 4);
                rs += __shfl_xor(rs, 8);
                lst[rg] += rs;
            }
            // ---- O += P @ V (both operands in permuted kv space) ----
            bf16x8 pa[2];
            #pragma unroll
            for (int ks = 0; ks < 2; ks++)
                pa[ks] = *(const bf16x8*)&Ps[pbase + lr * 72 + ks * 32 + lc * 8];
            __builtin_amdgcn_s_setprio(1);
            #pragma unroll
            for (int nf = 0; nf < 4; nf++) {
                #pragma unroll
                for (int ks = 0; ks < 2; ks++) {
                    int rr = nf * 16 + lr;
                    int cc = (lc + 4 * ks) ^ (rr & 7);
                    bf16x8 bv = *(const bf16x8*)&Vs[half][rr * 64 + cc * 8];
                    o[nf] = __builtin_amdgcn_mfma_f32_16x16x32_bf16(pa[ks], bv, o[nf], 0, 0, 0);
                }
            }
            __builtin_amdgcn_s_setprio(0);
        }
        __syncthreads();
    }

    // ---- merge halves (LSE merge); Osm aliases Ps (dead now) ----
    float* Osm = (float*)Ps;   // [4][16][68]
    if (half == 1) {
        #pragma unroll
        for (int rg = 0; rg < 4; rg++) {
            int row = lc * 4 + rg;
            if (lr == 0) { Mm[wq][row] = mst[rg]; Lm[wq][row] = lst[rg]; }
            #pragma unroll
            for (int nf = 0; nf < 4; nf++)
                Osm[(wq * 16 + row) * 68 + nf * 16 + lr] = o[nf][rg];
        }
    }
    __syncthreads();
    if (half == 0) {
        #pragma unroll
        for (int rg = 0; rg < 4; rg++) {
            int row = lc * 4 + rg;
            float m2 = Mm[wq][row], l2 = Lm[wq][row];
            float mn = fmaxf(mst[rg], m2);
            float a1 = exp2f(mst[rg] - mn);
            float a2 = exp2f(m2 - mn);
            float lm = lst[rg] * a1 + l2 * a2;
            float inv = 1.f / lm;
            #pragma unroll
            for (int nf = 0; nf < 4; nf++) {
                float ov = (o[nf][rg] * a1 + Osm[(wq * 16 + row) * 68 + nf * 16 + lr] * a2) * inv;
                aout[(size_t)(b * 2048 + q0 + qr + row) * 512 + h * 64 + nf * 16 + lr] =
                    f2bf(ov);
            }
        }
    }
}

// ---------------------------------------------------------------------------
extern "C" void kernel_launch(void* const* d_in, const int* in_sizes, int n_in,
                              void* d_out, int out_size, void* d_ws, size_t ws_size,
                              hipStream_t stream) {
    const float* x      = (const float*)d_in[0];
    const float* conv_w = (const float*)d_in[1];
    const float* conv_b = (const float*)d_in[2];
    const float* g1     = (const float*)d_in[3];
    const float* b1     = (const float*)d_in[4];
    const float* qkv_w  = (const float*)d_in[5];
    const float* qkv_b  = (const float*)d_in[6];
    const float* proj_w = (const float*)d_in[7];
    const float* proj_b = (const float*)d_in[8];
    const float* g2     = (const float*)d_in[9];
    const float* b2     = (const float*)d_in[10];
    const float* ffn_w1 = (const float*)d_in[11];
    const float* ffn_b1 = (const float*)d_in[12];
    const float* ffn_w2 = (const float*)d_in[13];
    const float* ffn_b2 = (const float*)d_in[14];
    const float* g3     = (const float*)d_in[15];
    const float* b3     = (const float*)d_in[16];
    float* out = (float*)d_out;

    char* p = (char*)d_ws;
    short* cwT   = (short*)p;  p += 786432 * 2;
    short* qkvT  = (short*)p;  p += 786432 * 2;
    short* projT = (short*)p;  p += 262144 * 2;
    short* f1T   = (short*)p;  p += 524288 * 2;
    short* f2T   = (short*)p;  p += 524288 * 2;
    short* xpad  = (short*)p;  p += 2099200 * 2;
    float* yb    = (float*)p;  p += 2097152 * 4;
    float* x1f   = (float*)p;  p += 2097152 * 4;
    short* x1b   = (short*)p;  p += 2097152 * 2;
    short* qkvb  = (short*)p;  p += 6291456 * 2;
    short* vTb   = (short*)p;  p += 2097152 * 2;
    // aliases of dead buffers:
    float* x2f     = x1f;   // x1f dead after proj epilogue
    short* x2b     = x1b;   // x1b dead after qkv GEMM
    short* attnout = xpad;  // xpad dead after conv GEMM
    short* hb      = qkvb;  // qkvb dead after attention

    cast_all<<<11272, 256, 0, stream>>>(conv_w, x, cwT, xpad);
    transpose_cast<<<2048, 256, 0, stream>>>(qkv_w, proj_w, ffn_w1, ffn_w2,
                                             qkvT, projT, f1T, f2T);
    gemm_mfma<M_CONV><<<dim3(64, 8), 256, 0, stream>>>(
        xpad, cwT, conv_b, x, yb, nullptr, 1536);
    ln2_kernel<<<4096, 256, 0, stream>>>(yb, g1, b1, x1f, x1b);
    gemm_mfma<M_QKV><<<dim3(64, 24), 256, 0, stream>>>(
        x1b, qkvT, qkv_b, nullptr, qkvb, vTb, 512);
    attn_mfma<<<512, 512, 0, stream>>>(qkvb, vTb, attnout);
    gemm_mfma<M_PROJ><<<dim3(64, 8), 256, 0, stream>>>(
        attnout, projT, proj_b, x1f, yb, nullptr, 512);
    ln2_kernel<<<4096, 256, 0, stream>>>(yb, g2, b2, x2f, x2b);
    gemm_mfma<M_FFN1><<<dim3(64, 16), 256, 0, stream>>>(
        x2b, f1T, ffn_b1, nullptr, hb, nullptr, 512);
    gemm_mfma<M_FFN2><<<dim3(64, 8), 256, 0, stream>>>(
        hb, f2T, ffn_b2, x2f, yb, nullptr, 1024);
    ln2_kernel<<<4096, 256, 0, stream>>>(yb, g3, b3, out, nullptr);
}

// Round 8
// 144.825 us; speedup vs baseline: 1.1125x; 1.1125x over previous
//
#include <hip/hip_runtime.h>
#include <hip/hip_bf16.h>

#define TT 2048

typedef __attribute__((ext_vector_type(4))) float f32x4;
typedef __attribute__((ext_vector_type(8))) __bf16 bf16x8;
typedef __attribute__((ext_vector_type(4))) short short4v;

enum { M_CONV = 0, M_QKV = 1, M_PROJ = 2, M_FFN1 = 3, M_FFN2 = 4 };

__device__ __forceinline__ void gload16(const void* g, void* l) {
    __builtin_amdgcn_global_load_lds(
        (__attribute__((address_space(1))) void*)g,
        (__attribute__((address_space(3))) void*)l, 16, 0, 0);
}

__device__ __forceinline__ short f2bf(float f) {
    unsigned u = __float_as_uint(f);
    u = (u + 0x7fffu + ((u >> 16) & 1u)) >> 16;
    return (short)u;
}

// ---------------------------------------------------------------------------
// conv_w cast + padded x cast
// ---------------------------------------------------------------------------
__global__ void cast_all(const float* __restrict__ conv_w, const float* __restrict__ x,
                         short* __restrict__ cwT, short* __restrict__ xpad) {
    int idx = blockIdx.x * 256 + threadIdx.x;
    if (idx < 786432) {                       // conv_w OIH -> [o][tap*512+i]
        int tap = idx >> 18, i = (idx >> 9) & 511, o = idx & 511;
        cwT[(size_t)o * 1536 + tap * 512 + i] = f2bf(conv_w[((size_t)o * 512 + i) * 3 + tap]);
        return;
    }
    idx -= 786432;
    if (idx < 2099200) {                      // x -> xpad [2][2050][512] bf16
        int i = idx & 511, rp = idx >> 9;
        int bb = rp / 2050, rr = rp - bb * 2050;
        int t = rr - 2;
        float v = (t >= 0) ? x[((size_t)(bb << 11) + t) * 512 + i] : 0.f;
        xpad[((size_t)bb * 2050 + rr) * 512 + i] = f2bf(v);
    }
}

// ---------------------------------------------------------------------------
// Coalesced [K][N] -> [N][K] bf16 transposes via 32x32 LDS tiles.
// ---------------------------------------------------------------------------
__global__ __launch_bounds__(256) void transpose_cast(
    const float* __restrict__ qkv_w, const float* __restrict__ proj_w,
    const float* __restrict__ f1w, const float* __restrict__ f2w,
    short* __restrict__ qkvT, short* __restrict__ projT,
    short* __restrict__ f1T, short* __restrict__ f2T) {
    int t = blockIdx.x;
    const float* src; short* dst; int K, N, lt;
    if (t < 768)       { src = qkv_w;  dst = qkvT;  K = 512;  N = 1536; lt = t; }
    else if (t < 1024) { src = proj_w; dst = projT; K = 512;  N = 512;  lt = t - 768; }
    else if (t < 1536) { src = f1w;    dst = f1T;   K = 512;  N = 1024; lt = t - 1024; }
    else               { src = f2w;    dst = f2T;   K = 1024; N = 512;  lt = t - 1536; }
    int ntn = N >> 5;
    int kt = lt / ntn, nt = lt - kt * ntn;
    int k0 = kt * 32, n0 = nt * 32;
    __shared__ float tile[32][33];
    int c = threadIdx.x & 31, r = threadIdx.x >> 5;
    #pragma unroll
    for (int i = 0; i < 4; i++)
        tile[r + i * 8][c] = src[(size_t)(k0 + r + i * 8) * N + n0 + c];
    __syncthreads();
    #pragma unroll
    for (int i = 0; i < 4; i++)
        dst[(size_t)(n0 + r + i * 8) * K + k0 + c] = f2bf(tile[c][r + i * 8]);
}

// ---------------------------------------------------------------------------
// Row LayerNorm, wave-per-row: 512 threads = 8 waves = 8 rows/block.
// ---------------------------------------------------------------------------
__global__ __launch_bounds__(512) void ln_row(const float* __restrict__ in,
                                              const float* __restrict__ g,
                                              const float* __restrict__ b,
                                              float* __restrict__ outf,
                                              short* __restrict__ outb) {
    int row = blockIdx.x * 8 + (threadIdx.x >> 6);
    int l = threadIdx.x & 63;
    const float* p = in + (size_t)row * 512 + l * 8;
    f32x4 v0 = *(const f32x4*)p;
    f32x4 v1 = *(const f32x4*)(p + 4);
    float s = 0.f, ss = 0.f;
    #pragma unroll
    for (int i = 0; i < 4; i++) { s += v0[i]; ss += v0[i] * v0[i]; }
    #pragma unroll
    for (int i = 0; i < 4; i++) { s += v1[i]; ss += v1[i] * v1[i]; }
    #pragma unroll
    for (int off = 1; off < 64; off <<= 1) {
        s  += __shfl_xor(s, off);
        ss += __shfl_xor(ss, off);
    }
    float mean = s * (1.f / 512);
    float var  = ss * (1.f / 512) - mean * mean;
    float rstd = rsqrtf(var + 1e-5f);
    f32x4 g0 = *(const f32x4*)(g + l * 8), g1 = *(const f32x4*)(g + l * 8 + 4);
    f32x4 b0 = *(const f32x4*)(b + l * 8), b1 = *(const f32x4*)(b + l * 8 + 4);
    f32x4 o0, o1;
    #pragma unroll
    for (int i = 0; i < 4; i++) {
        o0[i] = (v0[i] - mean) * rstd * g0[i] + b0[i];
        o1[i] = (v1[i] - mean) * rstd * g1[i] + b1[i];
    }
    float* q = outf + (size_t)row * 512 + l * 8;
    *(f32x4*)q = o0;
    *(f32x4*)(q + 4) = o1;
    if (outb) {
        short4v p0, p1;
        #pragma unroll
        for (int i = 0; i < 4; i++) { p0[i] = f2bf(o0[i]); p1[i] = f2bf(o1[i]); }
        *(short4v*)(outb + (size_t)row * 512 + l * 8) = p0;
        *(short4v*)(outb + (size_t)row * 512 + l * 8 + 4) = p1;
    }
}

// ---------------------------------------------------------------------------
// A-operand global address (handles conv's padded/3-tap layout)
// ---------------------------------------------------------------------------
template<int MODE>
__device__ __forceinline__ const short* a_ptr(const short* A, int m0, int r, int kk, int K) {
    if constexpr (MODE == M_CONV) {
        int row = m0 + r;
        int bb = row >> 11, t5 = row & 2047;
        int tap = kk >> 9, k2 = kk & 511;
        return A + ((size_t)(bb * 2050 + t5 + tap) * 512 + k2);
    } else {
        return A + ((size_t)(m0 + r) * K + kk);
    }
}

// ---------------------------------------------------------------------------
// bf16 MFMA GEMM (round-5 proven): BM=64, BN=64, BK=64, gload_lds staging,
// single LDS buffer, 4 waves (2x2), wave tile 32x32, chunk-swizzle both sides.
// ---------------------------------------------------------------------------
template<int MODE>
__global__ __launch_bounds__(256) void gemm_mfma(
    const short* __restrict__ A, const short* __restrict__ Bw,
    const float* __restrict__ bias, const float* __restrict__ res,
    void* __restrict__ Cout, short* __restrict__ vTb, int K) {
    __shared__ short As[64 * 64];
    __shared__ short Bs[64 * 64];
    const int tid = threadIdx.x;
    const int w = tid >> 6, l = tid & 63;
    const int wm = w >> 1, wn = w & 1;
    const int lr = l & 15, lc = l >> 4;
    const int m0 = blockIdx.x * 64, n0 = blockIdx.y * 64;
    f32x4 acc[2][2];
    #pragma unroll
    for (int mf = 0; mf < 2; mf++)
        #pragma unroll
        for (int nf = 0; nf < 2; nf++) acc[mf][nf] = (f32x4){0.f, 0.f, 0.f, 0.f};

    for (int k0 = 0; k0 < K; k0 += 64) {
        #pragma unroll
        for (int i = 0; i < 2; i++) {
            int u = i * 256 + tid;
            int r = u >> 3, c = (u & 7) ^ (r & 7);
            gload16(a_ptr<MODE>(A, m0, r, k0 + c * 8, K), (char*)As + u * 16);
            gload16(Bw + ((size_t)(n0 + r) * K + k0 + c * 8), (char*)Bs + u * 16);
        }
        __syncthreads();
        bf16x8 af[2][2], bfv[2][2];
        #pragma unroll
        for (int mf = 0; mf < 2; mf++)
            #pragma unroll
            for (int ks = 0; ks < 2; ks++) {
                int rr = wm * 32 + mf * 16 + lr;
                int cc = (ks * 4 + lc) ^ (rr & 7);
                af[mf][ks] = *(const bf16x8*)&As[rr * 64 + cc * 8];
            }
        #pragma unroll
        for (int nf = 0; nf < 2; nf++)
            #pragma unroll
            for (int ks = 0; ks < 2; ks++) {
                int rr = wn * 32 + nf * 16 + lr;
                int cc = (ks * 4 + lc) ^ (rr & 7);
                bfv[nf][ks] = *(const bf16x8*)&Bs[rr * 64 + cc * 8];
            }
        __builtin_amdgcn_s_setprio(1);
        #pragma unroll
        for (int nf = 0; nf < 2; nf++)
            #pragma unroll
            for (int ks = 0; ks < 2; ks++)
                #pragma unroll
                for (int mf = 0; mf < 2; mf++)
                    acc[mf][nf] = __builtin_amdgcn_mfma_f32_16x16x32_bf16(
                        af[mf][ks], bfv[nf][ks], acc[mf][nf], 0, 0, 0);
        __builtin_amdgcn_s_setprio(0);
        __syncthreads();
    }
    // epilogue
    #pragma unroll
    for (int mf = 0; mf < 2; mf++) {
        int row0 = m0 + wm * 32 + mf * 16 + lc * 4;
        #pragma unroll
        for (int nf = 0; nf < 2; nf++) {
            int col = n0 + wn * 32 + nf * 16 + lr;
            float bv = bias[col];
            if constexpr (MODE == M_CONV || MODE == M_PROJ || MODE == M_FFN2) {
                float* Cf = (float*)Cout;
                #pragma unroll
                for (int rg = 0; rg < 4; rg++) {
                    size_t off = (size_t)(row0 + rg) * 512 + col;
                    Cf[off] = acc[mf][nf][rg] + bv + res[off];
                }
            } else if constexpr (MODE == M_FFN1) {
                short* Cb = (short*)Cout;
                #pragma unroll
                for (int rg = 0; rg < 4; rg++)
                    Cb[(size_t)(row0 + rg) * 1024 + col] =
                        f2bf(fmaxf(acc[mf][nf][rg] + bv, 0.f));
            } else {  // M_QKV
                short* Cb = (short*)Cout;
                float v[4];
                #pragma unroll
                for (int rg = 0; rg < 4; rg++) {
                    v[rg] = acc[mf][nf][rg] + bv;
                    Cb[(size_t)(row0 + rg) * 1536 + col] = f2bf(v[rg]);
                }
                if (col >= 1024) {  // V transposed: vT[bh][d][t]
                    int vc = col - 1024, hh = vc >> 6, dd = vc & 63;
                    int bb = row0 >> 11, t5 = row0 & 2047;
                    short4v pk = {f2bf(v[0]), f2bf(v[1]), f2bf(v[2]), f2bf(v[3])};
                    *(short4v*)&vTb[((size_t)((bb << 3) + hh) * 64 + dd) * 2048 + t5] = pk;
                }
            }
        }
    }
}

// ---------------------------------------------------------------------------
// bf16 MFMA flash attention = round-5 structure (proven 43.7us) + LDS alias:
// one SM buffer; Qs staged once then held in regs (Qs region reused as Ps;
// Osm merge buffer aliases Ps). LDS ~51.5KB -> 3 blocks/CU.
// 512 blocks x 512 threads (8 waves), split-KV halves, LSE merge.
// NOTE: no pointer-array into __shared__ (hipcc static-initializer error);
// use offset arithmetic SM + half*4096 instead.
// ---------------------------------------------------------------------------
__global__ __launch_bounds__(512) void attn_mfma(const short* __restrict__ qkvb,
                                                 const short* __restrict__ vTb,
                                                 short* __restrict__ aout) {
    __shared__ short SM[25600];   // [0,8192)=Ks{0,1} | [8192,16384)=Vs{0,1} | [16384,...)=Ps/Qs/Osm
    __shared__ float Mm[4][16], Lm[4][16];
    const int tid = threadIdx.x;
    const int w = tid >> 6, l = tid & 63;
    const int half = w >> 2, wq = w & 3;
    const int lr = l & 15, lc = l >> 4;
    const int L = blockIdx.x;
    const int bh = L & 15;
    const int qt = 31 - (L >> 4);
    const int b = bh >> 3, h = bh & 7;
    const int qr = wq * 16, q0 = qt * 64;
    const int pbase = 16384 + w * (16 * 72);

    // prologue: stage Q through LDS once (into the Ps region), pull to regs
    {
        int u = tid, r = u >> 3, c = (u & 7) ^ (r & 7);
        gload16(qkvb + ((size_t)(b * 2048 + q0 + r) * 1536 + h * 64 + c * 8),
                (char*)&SM[16384] + u * 16);
    }
    __syncthreads();
    bf16x8 aq[2];
    #pragma unroll
    for (int ks = 0; ks < 2; ks++) {
        int rr = qr + lr;
        int cc = (lc + 4 * ks) ^ (rr & 7);
        aq[ks] = *(const bf16x8*)&SM[16384 + rr * 64 + cc * 8];
    }
    __syncthreads();   // all waves done reading Q; region becomes Ps

    f32x4 o[4];
    float mst[4], lst[4];
    #pragma unroll
    for (int nf = 0; nf < 4; nf++) o[nf] = (f32x4){0.f, 0.f, 0.f, 0.f};
    #pragma unroll
    for (int rg = 0; rg < 4; rg++) { mst[rg] = -1e30f; lst[rg] = 0.f; }

    const int NS = (qt + 2) >> 1;
    for (int ss = 0; ss < NS; ss++) {
        const int kt0 = 2 * ss, kt1 = 2 * ss + 1;
        {
            int u = tid, r = u >> 3, c = (u & 7) ^ (r & 7);
            gload16(qkvb + ((size_t)(b * 2048 + kt0 * 64 + r) * 1536 + 512 + h * 64 + c * 8),
                    (char*)&SM[0] + u * 16);
            gload16(vTb + ((size_t)(bh * 64 + r) * 2048 + kt0 * 64 + c * 8),
                    (char*)&SM[8192] + u * 16);
            if (kt1 <= qt) {
                gload16(qkvb + ((size_t)(b * 2048 + kt1 * 64 + r) * 1536 + 512 + h * 64 + c * 8),
                        (char*)&SM[4096] + u * 16);
                gload16(vTb + ((size_t)(bh * 64 + r) * 2048 + kt1 * 64 + c * 8),
                        (char*)&SM[12288] + u * 16);
            }
        }
        __syncthreads();
        const int mykt = 2 * ss + half;
        if (mykt <= qt) {
            const int kofs = half * 4096;
            const int vofs = 8192 + half * 4096;
            // ---- S = Q @ K^T ----
            f32x4 s[4];
            #pragma unroll
            for (int nf = 0; nf < 4; nf++) s[nf] = (f32x4){0.f, 0.f, 0.f, 0.f};
            __builtin_amdgcn_s_setprio(1);
            #pragma unroll
            for (int nf = 0; nf < 4; nf++) {
                #pragma unroll
                for (int ks = 0; ks < 2; ks++) {
                    int rr = nf * 16 + lr;
                    int cc = (lc + 4 * ks) ^ (rr & 7);
                    bf16x8 bk = *(const bf16x8*)&SM[kofs + rr * 64 + cc * 8];
                    s[nf] = __builtin_amdgcn_mfma_f32_16x16x32_bf16(aq[ks], bk, s[nf], 0, 0, 0);
                }
            }
            __builtin_amdgcn_s_setprio(0);
            // ---- online softmax with defer-max ----
            const bool diag = (mykt == qt);
            #pragma unroll
            for (int nf = 0; nf < 4; nf++) {
                #pragma unroll
                for (int rg = 0; rg < 4; rg++) {
                    float v = s[nf][rg] * 0.125f;
                    if (diag && (nf * 16 + lr > qr + lc * 4 + rg)) v = -1e30f;
                    s[nf][rg] = v;
                }
            }
            float rm[4];
            int ok = 1;
            #pragma unroll
            for (int rg = 0; rg < 4; rg++) {
                float m_ = fmaxf(fmaxf(s[0][rg], s[1][rg]), fmaxf(s[2][rg], s[3][rg]));
                m_ = fmaxf(m_, __shfl_xor(m_, 1));
                m_ = fmaxf(m_, __shfl_xor(m_, 2));
                m_ = fmaxf(m_, __shfl_xor(m_, 4));
                m_ = fmaxf(m_, __shfl_xor(m_, 8));
                rm[rg] = m_;
                ok &= (m_ <= mst[rg] + 8.f);
            }
            if (!__all(ok)) {
                #pragma unroll
                for (int rg = 0; rg < 4; rg++) {
                    float mn = fmaxf(mst[rg], rm[rg]);
                    float alpha = __expf(mst[rg] - mn);
                    mst[rg] = mn;
                    lst[rg] *= alpha;
                    #pragma unroll
                    for (int nf = 0; nf < 4; nf++) o[nf][rg] *= alpha;
                }
            }
            #pragma unroll
            for (int rg = 0; rg < 4; rg++) {
                float p0 = __expf(s[0][rg] - mst[rg]);
                float p1 = __expf(s[1][rg] - mst[rg]);
                float p2 = __expf(s[2][rg] - mst[rg]);
                float p3 = __expf(s[3][rg] - mst[rg]);
                int prow = pbase + (lc * 4 + rg) * 72;
                SM[prow      + lr] = f2bf(p0);
                SM[prow + 16 + lr] = f2bf(p1);
                SM[prow + 32 + lr] = f2bf(p2);
                SM[prow + 48 + lr] = f2bf(p3);
                float rs = p0 + p1 + p2 + p3;
                rs += __shfl_xor(rs, 1);
                rs += __shfl_xor(rs, 2);
                rs += __shfl_xor(rs, 4);
                rs += __shfl_xor(rs, 8);
                lst[rg] += rs;
            }
            // ---- O += P @ V ----
            bf16x8 pa[2];
            #pragma unroll
            for (int ks = 0; ks < 2; ks++)
                pa[ks] = *(const bf16x8*)&SM[pbase + lr * 72 + ks * 32 + lc * 8];
            __builtin_amdgcn_s_setprio(1);
            #pragma unroll
            for (int nf = 0; nf < 4; nf++) {
                #pragma unroll
                for (int ks = 0; ks < 2; ks++) {
                    int rr = nf * 16 + lr;
                    int cc = (lc + 4 * ks) ^ (rr & 7);
                    bf16x8 bv = *(const bf16x8*)&SM[vofs + rr * 64 + cc * 8];
                    o[nf] = __builtin_amdgcn_mfma_f32_16x16x32_bf16(pa[ks], bv, o[nf], 0, 0, 0);
                }
            }
            __builtin_amdgcn_s_setprio(0);
        }
        __syncthreads();
    }

    // ---- merge halves (LSE merge); Osm aliases Ps region (dead now) ----
    float* Osm = (float*)&SM[16384];   // [4][16][68] floats = 17408B < 18432B
    if (half == 1) {
        #pragma unroll
        for (int rg = 0; rg < 4; rg++) {
            int row = lc * 4 + rg;
            if (lr == 0) { Mm[wq][row] = mst[rg]; Lm[wq][row] = lst[rg]; }
            #pragma unroll
            for (int nf = 0; nf < 4; nf++)
                Osm[(wq * 16 + row) * 68 + nf * 16 + lr] = o[nf][rg];
        }
    }
    __syncthreads();
    if (half == 0) {
        #pragma unroll
        for (int rg = 0; rg < 4; rg++) {
            int row = lc * 4 + rg;
            float m2 = Mm[wq][row], l2 = Lm[wq][row];
            float mn = fmaxf(mst[rg], m2);
            float a1 = __expf(mst[rg] - mn);
            float a2 = __expf(m2 - mn);
            float lm = lst[rg] * a1 + l2 * a2;
            float inv = 1.f / lm;
            #pragma unroll
            for (int nf = 0; nf < 4; nf++) {
                float ov = (o[nf][rg] * a1 + Osm[(wq * 16 + row) * 68 + nf * 16 + lr] * a2) * inv;
                aout[(size_t)(b * 2048 + q0 + qr + row) * 512 + h * 64 + nf * 16 + lr] =
                    f2bf(ov);
            }
        }
    }
}

// ---------------------------------------------------------------------------
extern "C" void kernel_launch(void* const* d_in, const int* in_sizes, int n_in,
                              void* d_out, int out_size, void* d_ws, size_t ws_size,
                              hipStream_t stream) {
    const float* x      = (const float*)d_in[0];
    const float* conv_w = (const float*)d_in[1];
    const float* conv_b = (const float*)d_in[2];
    const float* g1     = (const float*)d_in[3];
    const float* b1     = (const float*)d_in[4];
    const float* qkv_w  = (const float*)d_in[5];
    const float* qkv_b  = (const float*)d_in[6];
    const float* proj_w = (const float*)d_in[7];
    const float* proj_b = (const float*)d_in[8];
    const float* g2     = (const float*)d_in[9];
    const float* b2     = (const float*)d_in[10];
    const float* ffn_w1 = (const float*)d_in[11];
    const float* ffn_b1 = (const float*)d_in[12];
    const float* ffn_w2 = (const float*)d_in[13];
    const float* ffn_b2 = (const float*)d_in[14];
    const float* g3     = (const float*)d_in[15];
    const float* b3     = (const float*)d_in[16];
    float* out = (float*)d_out;

    char* p = (char*)d_ws;
    short* cwT   = (short*)p;  p += 786432 * 2;
    short* qkvT  = (short*)p;  p += 786432 * 2;
    short* projT = (short*)p;  p += 262144 * 2;
    short* f1T   = (short*)p;  p += 524288 * 2;
    short* f2T   = (short*)p;  p += 524288 * 2;
    short* xpad  = (short*)p;  p += 2099200 * 2;
    float* yb    = (float*)p;  p += 2097152 * 4;
    float* x1f   = (float*)p;  p += 2097152 * 4;
    short* x1b   = (short*)p;  p += 2097152 * 2;
    short* qkvb  = (short*)p;  p += 6291456 * 2;
    short* vTb   = (short*)p;  p += 2097152 * 2;
    // aliases of dead buffers:
    float* x2f     = x1f;   // x1f dead after proj epilogue
    short* x2b     = x1b;   // x1b dead after qkv GEMM
    short* attnout = xpad;  // xpad dead after conv GEMM
    short* hb      = qkvb;  // qkvb dead after attention

    cast_all<<<11272, 256, 0, stream>>>(conv_w, x, cwT, xpad);
    transpose_cast<<<2048, 256, 0, stream>>>(qkv_w, proj_w, ffn_w1, ffn_w2,
                                             qkvT, projT, f1T, f2T);
    gemm_mfma<M_CONV><<<dim3(64, 8), 256, 0, stream>>>(
        xpad, cwT, conv_b, x, yb, nullptr, 1536);
    ln_row<<<512, 512, 0, stream>>>(yb, g1, b1, x1f, x1b);
    gemm_mfma<M_QKV><<<dim3(64, 24), 256, 0, stream>>>(
        x1b, qkvT, qkv_b, nullptr, qkvb, vTb, 512);
    attn_mfma<<<512, 512, 0, stream>>>(qkvb, vTb, attnout);
    gemm_mfma<M_PROJ><<<dim3(64, 8), 256, 0, stream>>>(
        attnout, projT, proj_b, x1f, yb, nullptr, 512);
    ln_row<<<512, 512, 0, stream>>>(yb, g2, b2, x2f, x2b);
    gemm_mfma<M_FFN1><<<dim3(64, 16), 256, 0, stream>>>(
        x2b, f1T, ffn_b1, nullptr, hb, nullptr, 512);
    gemm_mfma<M_FFN2><<<dim3(64, 8), 256, 0, stream>>>(
        hb, f2T, ffn_b2, x2f, yb, nullptr, 1024);
    ln_row<<<512, 512, 0, stream>>>(yb, g3, b3, out, nullptr);
}